// Round 8
// baseline (777.566 us; speedup 1.0000x reference)
//
#include <hip/hip_runtime.h>
#include <cfloat>

typedef _Float16 half8 __attribute__((ext_vector_type(8)));
typedef float    f32x4 __attribute__((ext_vector_type(4)));

#define N_ROWS 65536
#define DIM    256
#define KCODES 4096
#define BM 128
#define BK 32
#define NITER 128              // 16 pairs x 8 slices

// d_ws layout (bytes): csq[4096]f32 | xsq[65536]f32 | ch[1M]f16 | cl[1M]f16
#define WS_CSQ 0
#define WS_XSQ 16384
#define WS_CH  278528
#define WS_CL  2375680

// async global->LDS, 16B per lane, LDS dst = uniform base + lane*16
#define GLDS(g, l) __builtin_amdgcn_global_load_lds(                       \
    (const __attribute__((address_space(1))) unsigned int*)(g),            \
    (__attribute__((address_space(3))) unsigned int*)(l), 16, 0, 0)

// ---- Prologue: csq (k-ascending fmaf chain, matches ref) + cb -> f16 hi/lo planes (x64) ----
__global__ void prep_codes(const float* __restrict__ cb, float* __restrict__ csq,
                           _Float16* __restrict__ ch, _Float16* __restrict__ cl) {
    __shared__ float As[32 * DIM];   // 32KB
    const int t = threadIdx.x;
    const int c0 = blockIdx.x * 32;
    #pragma unroll
    for (int i = 0; i < 8; ++i) {
        int r = 4 * i + (t >> 6), d4 = (t & 63) * 4;
        *(float4*)&As[r * DIM + d4] = *(const float4*)&cb[(size_t)(c0 + r) * DIM + d4];
    }
    __syncthreads();
    {
        const int r = t >> 3;
        const int k0 = (t & 7) * 32;
        const float* src = &As[r * DIM + k0];
        _Float16* dh = &ch[(size_t)(c0 + r) * DIM + k0];
        _Float16* dl = &cl[(size_t)(c0 + r) * DIM + k0];
        #pragma unroll
        for (int i = 0; i < 4; ++i) {
            half8 hv, lv;
            #pragma unroll
            for (int j = 0; j < 8; ++j) {
                float sv = src[i * 8 + j] * 64.f;
                _Float16 h = (_Float16)sv;
                hv[j] = h; lv[j] = (_Float16)(sv - (float)h);
            }
            *(half8*)(dh + i * 8) = hv;
            *(half8*)(dl + i * 8) = lv;
        }
    }
    if (t < 32) {
        const float* row = &As[t * DIM];
        float s = 0.f;
        for (int k = 0; k < DIM; ++k) s = fmaf(row[k], row[k], s);   // k-ascending chain
        csq[c0 + t] = s;
    }
}

// ---- Main: fused x-prep + chunk-paired 3-split f16 MFMA GEMM + fused argmin ----
// 128 iters of (pair, slice): A[sl] single-buffered 16KB, B pair-tile (256 codes)
// double-buffered 2x32KB = 80KB LDS (2 blocks/CU). 24 frag-reads + 12 GLDS feed
// 96 MFMAs (A-frags shared by both chunks) -> LDS bytes/MFMA cut 25%.
__global__ __launch_bounds__(256, 2)
void vq_mfma(const float* __restrict__ x, const float* __restrict__ cb,
             const float* __restrict__ csq,
             const _Float16* __restrict__ ch, const _Float16* __restrict__ cl,
             float* __restrict__ xsqg, float* out_q, float* __restrict__ out_idx) {
    __shared__ __align__(1024) char SMEM[81920];
    _Float16* AhS = (_Float16*)SMEM;                 // 8KB  [128][32]
    _Float16* AlS = (_Float16*)(SMEM + 8192);        // 8KB
    _Float16* BhS = (_Float16*)(SMEM + 16384);       // 32KB [2][256][32]
    _Float16* BlS = (_Float16*)(SMEM + 49152);       // 32KB

    const int t = threadIdx.x;
    const int lane = t & 63, wave = t >> 6;
    const int wy = wave >> 1, wx = wave & 1;
    const int m = lane & 15, q = lane >> 4;   // MFMA: A/B row = m, k-granule = q; C: row=4q+e, col=m
    const int n0 = blockIdx.x * BM;
    const int swz = (q ^ ((m + (m >> 2)) & 3)) * 8;   // frag-read granule offset (f16 units)

    // ======== fused x-prep: 4 groups of 32 rows (verified r3-r7; xsq -> global) ========
    {
        float*  prepF = (float*)SMEM;                  // 32KB
        double* dtmp  = (double*)(SMEM + 49152);       // 1KB (BlS region)
        char*   xqw   = (char*)out_q;
        for (int g = 0; g < 4; ++g) {
            const int r0 = g * 32;
            #pragma unroll
            for (int i = 0; i < 8; ++i) {
                int r = 4 * i + (t >> 6), d4 = (t & 63) * 4;
                *(float4*)&prepF[r * DIM + d4] =
                    *(const float4*)&x[(size_t)(n0 + r0 + r) * DIM + d4];
            }
            __syncthreads();
            {
                const int r = t >> 3;
                const int col8 = (t & 7) * 8;
                char* dst = xqw + (((size_t)(n0 + r0 + r)) << 10) + (size_t)(col8 * 2);
                const float* src = &prepF[r * DIM + col8];
                #pragma unroll
                for (int i = 0; i < 4; ++i) {
                    half8 hv, lv;
                    #pragma unroll
                    for (int j = 0; j < 8; ++j) {
                        float v = src[i * 64 + j];
                        _Float16 h = (_Float16)v;
                        hv[j] = h; lv[j] = (_Float16)(v - (float)h);
                    }
                    *(half8*)(dst + i * 128) = hv;          // hi plane
                    *(half8*)(dst + 512 + i * 128) = lv;    // lo plane
                }
            }
            if (t < 128) {
                int r = t >> 2, part = t & 3;
                const float* ap = &prepF[r * DIM + 64 * part];
                double s = 0.0;
                for (int k = 0; k < 64; ++k) { double v = (double)ap[k]; s = fma(v, v, s); }
                dtmp[t] = s;
            }
            __syncthreads();
            if (t < 32)
                xsqg[n0 + r0 + t] = (float)((dtmp[4*t] + dtmp[4*t+1]) + (dtmp[4*t+2] + dtmp[4*t+3]));
            __syncthreads();
        }
    }
    // plane + xsq stores must be visible before glds / epilogue reads
    asm volatile("s_waitcnt vmcnt(0)" ::: "memory");
    __syncthreads();

    // ======== staging addressing (granule pre-swizzle, verified) ========
    const int rq  = lane >> 2;
    const int gph = lane & 3;
    const int glog = ((gph ^ ((rq + (rq >> 2)) & 3)) << 4);   // source granule, bytes
    const char* aBase  = (const char*)out_q + (((size_t)(n0 + wave * 32 + rq)) << 10) + glog;
    const char* bBaseH = (const char*)ch + (((size_t)(wave * 64 + rq)) << 9) + glog;
    const char* bBaseL = (const char*)cl + (((size_t)(wave * 64 + rq)) << 9) + glog;

    // A slice s -> AhS/AlS (single buffer). rows wave*32+rq(+16)
#define ASTAGE(s) do {                                                       \
    const char* a_ = aBase + (size_t)((s) * 64);                             \
    _Float16* Ah_ = AhS + wave * 1024;                                       \
    _Float16* Al_ = AlS + wave * 1024;                                       \
    GLDS(a_,           Ah_);                                                 \
    GLDS(a_ + 16384,   Ah_ + 512);                                           \
    GLDS(a_ + 512,     Al_);                                                 \
    GLDS(a_ + 16896,   Al_ + 512);                                           \
} while (0)

    // B pair-tile (256 codes) slice s -> buf nb. rows wave*64+rq(+16,+32,+48)
#define BSTAGE(p2, s, nb) do {                                               \
    const size_t bo_ = (size_t)(p2) * 131072 + (size_t)((s) * 64);           \
    const char* bh_ = bBaseH + bo_;                                          \
    const char* bl_ = bBaseL + bo_;                                          \
    _Float16* Bh_ = BhS + (nb) * 8192 + wave * 2048;                         \
    _Float16* Bl_ = BlS + (nb) * 8192 + wave * 2048;                         \
    GLDS(bh_,          Bh_);                                                 \
    GLDS(bh_ + 8192,   Bh_ + 512);                                           \
    GLDS(bh_ + 16384,  Bh_ + 1024);                                          \
    GLDS(bh_ + 24576,  Bh_ + 1536);                                          \
    GLDS(bl_,          Bl_);                                                 \
    GLDS(bl_ + 8192,   Bl_ + 512);                                           \
    GLDS(bl_ + 16384,  Bl_ + 1024);                                          \
    GLDS(bl_ + 24576,  Bl_ + 1536);                                          \
} while (0)

#define SWEEP(AF, BF, ACC)                                                   \
    _Pragma("unroll")                                                        \
    for (int tc = 0; tc < 4; ++tc)                                           \
        _Pragma("unroll")                                                    \
        for (int tr = 0; tr < 4; ++tr)                                       \
            ACC[tr][tc] = __builtin_amdgcn_mfma_f32_16x16x32_f16(AF[tr], BF[tc], ACC[tr][tc], 0, 0, 0)

    const int a_rd = (64 * wy + m) * 32 + swz;     // + tr*512   (f16 units)
    const int b_rd = (64 * wx + m) * 32 + swz;     // + cbuf*8192 + cc*4096 + tc*512

    float best[16]; int bidx[16];
    #pragma unroll
    for (int s = 0; s < 16; ++s) { best[s] = FLT_MAX; bidx[s] = 0; }

    // prologue: A(0) + B pair-slices 0,1 in flight; drain; enter loop
    ASTAGE(0);
    BSTAGE(0, 0, 0);
    BSTAGE(0, 1, 1);
    asm volatile("s_waitcnt vmcnt(0)" ::: "memory");
    __builtin_amdgcn_s_barrier();
    __builtin_amdgcn_sched_barrier(0);

    f32x4 acc0[4][4], acc1[4][4];

    #pragma unroll 2
    for (int j = 0; j < NITER; ++j) {
        const int cbuf = j & 1;
        const int p2 = j >> 3, sl = j & 7;
        if (sl == 0) {
            #pragma unroll
            for (int tr = 0; tr < 4; ++tr)
                #pragma unroll
                for (int tc = 0; tc < 4; ++tc) {
                    acc0[tr][tc] = (f32x4){0.f, 0.f, 0.f, 0.f};
                    acc1[tr][tc] = (f32x4){0.f, 0.f, 0.f, 0.f};
                }
        }
        const _Float16* Bh = BhS + cbuf * 8192;
        const _Float16* Bl = BlS + cbuf * 8192;

        // frag reads: A (shared by both chunks) + chunk0 B
        half8 aH[4], aL[4], b0h[4], b0l[4];
        #pragma unroll
        for (int tr = 0; tr < 4; ++tr) aH[tr] = *(const half8*)&AhS[a_rd + tr * 512];
        #pragma unroll
        for (int tc = 0; tc < 4; ++tc) b0h[tc] = *(const half8*)&Bh[b_rd + tc * 512];
        #pragma unroll
        for (int tc = 0; tc < 4; ++tc) b0l[tc] = *(const half8*)&Bl[b_rd + tc * 512];
        #pragma unroll
        for (int tr = 0; tr < 4; ++tr) aL[tr] = *(const half8*)&AlS[a_rd + tr * 512];

        // chunk0 sweeps (HH, HL, LH — bit-exact order)
        SWEEP(aH, b0h, acc0);
        SWEEP(aH, b0l, acc0);
        SWEEP(aL, b0h, acc0);

        // chunk1 B frags (reuse b0 registers; DS reads pinned below chunk0 via mask)
        __builtin_amdgcn_sched_barrier(0x0F);   // ALU/VALU/SALU/MFMA may cross; DS/VMEM may not
        half8 b1h[4], b1l[4];
        #pragma unroll
        for (int tc = 0; tc < 4; ++tc) b1h[tc] = *(const half8*)&Bh[b_rd + 4096 + tc * 512];
        #pragma unroll
        for (int tc = 0; tc < 4; ++tc) b1l[tc] = *(const half8*)&Bl[b_rd + 4096 + tc * 512];

        // rendezvous: all waves done reading Abuf + Bbuf[cbuf] -> safe to overwrite
        asm volatile("s_waitcnt lgkmcnt(0)" ::: "memory");
        __builtin_amdgcn_s_barrier();
        __builtin_amdgcn_sched_barrier(0);
        if (j <= NITER - 2) ASTAGE((j + 1) & 7);
        if (j <= NITER - 3) { const int jn = j + 2; BSTAGE(jn >> 3, jn & 7, cbuf); }
        __builtin_amdgcn_sched_barrier(0);

        // chunk1 sweeps (cover the stages: ~48 MFMA before vmcnt)
        SWEEP(aH, b1h, acc1);
        SWEEP(aH, b1l, acc1);
        SWEEP(aL, b1h, acc1);

        if (sl == 7) {
            // pair epilogue: dist + running argmin, chunks ascending (2*p2 then 2*p2+1)
            float xr[16];
            #pragma unroll
            for (int s = 0; s < 16; ++s)
                xr[s] = xsqg[n0 + 64 * wy + 16 * (s >> 2) + 4 * q + (s & 3)];
            {
                const int cb0 = 256 * p2 + 64 * wx;
                float cs[4];
                #pragma unroll
                for (int tc = 0; tc < 4; ++tc) cs[tc] = csq[cb0 + 16 * tc + m];
                #pragma unroll
                for (int tc = 0; tc < 4; ++tc) {
                    int c = cb0 + 16 * tc + m;
                    #pragma unroll
                    for (int tr = 0; tr < 4; ++tr)
                        #pragma unroll
                        for (int e = 0; e < 4; ++e) {
                            float dot = acc0[tr][tc][e] * 0.015625f;     // exact /64
                            float d = fmaf(-2.f, dot, xr[tr * 4 + e]) + cs[tc];
                            int s = tr * 4 + e;
                            if (d < best[s]) { best[s] = d; bidx[s] = c; }
                        }
                }
            }
            {
                const int cb1 = 256 * p2 + 128 + 64 * wx;
                float cs[4];
                #pragma unroll
                for (int tc = 0; tc < 4; ++tc) cs[tc] = csq[cb1 + 16 * tc + m];
                #pragma unroll
                for (int tc = 0; tc < 4; ++tc) {
                    int c = cb1 + 16 * tc + m;
                    #pragma unroll
                    for (int tr = 0; tr < 4; ++tr)
                        #pragma unroll
                        for (int e = 0; e < 4; ++e) {
                            float dot = acc1[tr][tc][e] * 0.015625f;     // exact /64
                            float d = fmaf(-2.f, dot, xr[tr * 4 + e]) + cs[tc];
                            int s = tr * 4 + e;
                            if (d < best[s]) { best[s] = d; bidx[s] = c; }
                        }
                }
            }
        }

        if (j < NITER - 1) {
            // retire A(j+1), B(j+2) stages; next iter's frags guaranteed in LDS
            asm volatile("s_waitcnt vmcnt(0)" ::: "memory");
            __builtin_amdgcn_s_barrier();
            __builtin_amdgcn_sched_barrier(0);
        }
    }

    // reduce across the 16 lanes of each quad-group (same physical rows)
    #pragma unroll
    for (int s = 0; s < 16; ++s) {
        float v = best[s]; int idx = bidx[s];
        #pragma unroll
        for (int off = 1; off < 16; off <<= 1) {
            float v2 = __shfl_xor(v, off);
            int   i2 = __shfl_xor(idx, off);
            if (v2 < v || (v2 == v && i2 < idx)) { v = v2; idx = i2; }
        }
        best[s] = v; bidx[s] = idx;
    }
    __syncthreads();                      // staging LDS free now
    float* rb = (float*)SMEM;             // [row][wx] candidates (1KB)
    int*   ri = (int*)(SMEM + 16384);     // (1KB)
    {
        int s = m;                        // lane writes slot == lane&15 (bijective over rows)
        int row_local = 64 * wy + 16 * (s >> 2) + 4 * q + (s & 3);
        rb[row_local * 2 + wx] = best[s];
        ri[row_local * 2 + wx] = bidx[s];
    }
    __syncthreads();
    int* widx = (int*)(SMEM + 32768);
    if (t < BM) {
        float d0 = rb[t * 2], d1 = rb[t * 2 + 1];
        int   i0 = ri[t * 2], i1 = ri[t * 2 + 1];
        int w = (d1 < d0 || (d1 == d0 && i1 < i0)) ? i1 : i0;
        widx[t] = w;
        out_idx[n0 + t] = (float)w;
    }
    __syncthreads();
    // gather winners, coalesced float4 (overwrites this block's packed-x scratch — all A reads done)
    const int l4 = t & 63, rg = t >> 6;
    #pragma unroll 4
    for (int i = 0; i < 32; ++i) {
        int r = rg + 4 * i;
        *(float4*)&out_q[(size_t)(n0 + r) * DIM + l4 * 4] =
            *(const float4*)&cb[(size_t)widx[r] * DIM + l4 * 4];
    }
#undef ASTAGE
#undef BSTAGE
#undef SWEEP
}

extern "C" void kernel_launch(void* const* d_in, const int* in_sizes, int n_in,
                              void* d_out, int out_size, void* d_ws, size_t ws_size,
                              hipStream_t stream) {
    const float* x  = (const float*)d_in[0];
    const float* cb = (const float*)d_in[1];
    float* out_q   = (float*)d_out;
    float* out_idx = (float*)d_out + (size_t)N_ROWS * DIM;

    float*    csq  = (float*)((char*)d_ws + WS_CSQ);
    float*    xsqg = (float*)((char*)d_ws + WS_XSQ);
    _Float16* ch   = (_Float16*)((char*)d_ws + WS_CH);
    _Float16* cl   = (_Float16*)((char*)d_ws + WS_CL);

    prep_codes<<<KCODES / 32, 256, 0, stream>>>(cb, csq, ch, cl);
    vq_mfma<<<N_ROWS / BM, 256, 0, stream>>>(x, cb, csq, ch, cl, xsqg, out_q, out_idx);
}